// Round 5
// baseline (548.256 us; speedup 1.0000x reference)
//
#include <hip/hip_runtime.h>
#include <cmath>

#define NN 200000
#define NE 600000
#define FSTR 520  // LDS frag stride in shorts: 1040 B = 65*16 B. The +16 B pad makes the
                  // store-side (lane>>4)&1 stride 1040 B = bank+4 (vs 1024 B = bank+0),
                  // cutting C->frag store conflicts from 4-way to 2-way (free).

typedef __bf16 bf16x8 __attribute__((ext_vector_type(8)));
typedef float f32x16 __attribute__((ext_vector_type(16)));

#define LOG2E 1.44269504088896340736f
__device__ __forceinline__ float fexp2(float x) { return __builtin_amdgcn_exp2f(x); }
__device__ __forceinline__ float frcp(float x) { return __builtin_amdgcn_rcpf(x); }
__device__ __forceinline__ float sigm(float v) { return frcp(1.0f + fexp2(-LOG2E * v)); }
__device__ __forceinline__ float ftanh(float v) {
  float t = fexp2(-2.0f * LOG2E * fabsf(v));
  float r = (1.0f - t) * frcp(1.0f + t);
  return __builtin_copysignf(r, v);
}
__device__ __forceinline__ float eluf(float v) { return v > 0.0f ? v : fexp2(LOG2E * v) - 1.0f; }

__device__ __forceinline__ unsigned short bfr(float f) {  // f32 -> bf16 RNE
  unsigned u = __float_as_uint(f);
  u += 0x7FFFu + ((u >> 16) & 1u);
  return (unsigned short)(u >> 16);
}
__device__ __forceinline__ void bsplit(float v, unsigned short& hi, unsigned short& lo) {
  unsigned short h = bfr(v);
  float hf = __uint_as_float(((unsigned)h) << 16);
  hi = h;
  lo = bfr(v - hf);
}

// ---------------- ws layout (float offsets) ----------------
// deg(int) @25,600,000 ; rwt0[128] @25,800,000 ; rwh0[384] @25,800,128 ;
// packed weight frags (shorts) @float 25,800,512:
//   w0ph 49152 | w0pl 49152 | w1ph 16384 | w1pl 16384 | w2ph 98304 | w2pl 98304
// Weight frag order (32x32x16), 512-short frags (global mem, no bank issue):
//   frag[((nt*8+ks)*64+lane)*8+j] = W[nt*32+(lane&31)][ks*16+(lane>>5)*8+j]

// ---- one prologue kernel: hist (blocks 0..2343) | prep (2344..2471) | pack (2472..2551)
__global__ __launch_bounds__(256) void prologue_kernel(
    const int* __restrict__ dst, int* __restrict__ deg,
    const float* __restrict__ attw0, const float* __restrict__ whh0,
    float* __restrict__ rwt0, float* __restrict__ rwh0,
    const float* __restrict__ wih0, const float* __restrict__ tw1,
    const float* __restrict__ wih1, const float* __restrict__ whh1f,
    unsigned short* __restrict__ w0ph, unsigned short* __restrict__ w0pl,
    unsigned short* __restrict__ w1ph, unsigned short* __restrict__ w1pl,
    unsigned short* __restrict__ w2ph, unsigned short* __restrict__ w2pl) {
  const int bid = blockIdx.x;
  const int tid = threadIdx.x;
  if (bid < 2344) {  // histogram of dst -> deg
    int e = bid * 256 + tid;
    if (e < NE) atomicAdd(&deg[dst[e]], 1);
    return;
  }
  if (bid < 2472) {  // row sums of attw0 (128 rows) and whh0 (384 rows), 1 wave/row
    int gw = (bid - 2344) * 4 + (tid >> 6);  // 0..511
    int lane = tid & 63;
    const float* row = (gw < 128) ? (attw0 + (size_t)gw * 128)
                                  : (whh0 + (size_t)(gw - 128) * 128);
    float2 v = ((const float2*)row)[lane];
    float a = v.x + v.y;
#pragma unroll
    for (int o = 1; o < 64; o <<= 1) a += __shfl_xor(a, o, 64);
    if (lane == 0) {
      if (gw < 128) rwt0[gw] = a;
      else rwh0[gw - 128] = a;
    }
    return;
  }
  // pack weights into MFMA B-frag order, split hi/lo bf16
  int g = (bid - 2472) * 256 + tid;
  if (g >= 20480) return;
  unsigned short *PH, *PL;
  const float* row;
  int l;
  if (g < 6144) { l = g; PH = w0ph; PL = w0pl; }
  else if (g < 8192) { l = g - 6144; PH = w1ph; PL = w1pl; }
  else { l = g - 8192; PH = w2ph; PL = w2pl; }
  int lane = l & 63, ks = (l >> 6) & 7, nt = l >> 9;
  int n = nt * 32 + (lane & 31);
  int k0 = ks * 16 + (lane >> 5) * 8;
  if (g < 6144) row = wih0 + n * 128;
  else if (g < 8192) row = tw1 + n * 128;
  else row = (n < 384) ? wih1 + n * 128 : whh1f + (n - 384) * 128;
  unsigned uh[4], ul[4];
#pragma unroll
  for (int p = 0; p < 4; p++) {
    unsigned short ah, al, bh, bl;
    bsplit(row[k0 + 2 * p], ah, al);
    bsplit(row[k0 + 2 * p + 1], bh, bl);
    uh[p] = (unsigned)ah | ((unsigned)bh << 16);
    ul[p] = (unsigned)al | ((unsigned)bl << 16);
  }
  *(uint4*)&PH[l * 8] = make_uint4(uh[0], uh[1], uh[2], uh[3]);
  *(uint4*)&PL[l * 8] = make_uint4(ul[0], ul[1], ul[2], ul[3]);
}

#define MFMA3(accv, ah, al, bh, bl)                                          \
  accv = __builtin_amdgcn_mfma_f32_32x32x16_bf16(ah, bh, accv, 0, 0, 0);     \
  accv = __builtin_amdgcn_mfma_f32_32x32x16_bf16(ah, bl, accv, 0, 0, 0);     \
  accv = __builtin_amdgcn_mfma_f32_32x32x16_bf16(al, bh, accv, 0, 0, 0);

// ---------------- fused both layers: M=64 nodes/block, 512 threads (8 waves) ------
// Wave (mg = wv&1, cb = wv>>1): rows mg*32..+32, cols cb*32..+32.
__global__ __launch_bounds__(512, 4) void fused_kernel(
    const float* __restrict__ x,
    const float* __restrict__ tb0, const float* __restrict__ tb1,
    const unsigned short* __restrict__ w0ph, const unsigned short* __restrict__ w0pl,
    const unsigned short* __restrict__ w1ph, const unsigned short* __restrict__ w1pl,
    const unsigned short* __restrict__ w2ph, const unsigned short* __restrict__ w2pl,
    const float* __restrict__ bih0, const float* __restrict__ bhh0,
    const float* __restrict__ rwt0, const float* __restrict__ rwh0,
    const float* __restrict__ bih1, const float* __restrict__ bhh1,
    const int* __restrict__ deg, float* __restrict__ out) {
  extern __shared__ unsigned short smem[];
  unsigned short* csh = smem;               // 16*FSTR = 8320 shorts (cs0, reused as cs1)
  unsigned short* csl = smem + 8320;
  unsigned short* hfh = smem + 16640;       // h frags, live to the end
  unsigned short* hfl = smem + 24960;       // total 33280 shorts = 66560 B
  __shared__ float s_lds[64];
  __shared__ float deg_lds[64];

  const int tid = threadIdx.x;
  const int lane = tid & 63;
  const int wv = tid >> 6;
  const int mg = wv & 1;
  const int cb = wv >> 1;
  const int n0 = blockIdx.x * 64;

  if (tid < 64) deg_lds[tid] = (float)deg[n0 + tid];

  // s_m = rowsum(x[m])
  {
    int m = tid >> 3, c = (tid & 7) * 16;
    const float4* xr = (const float4*)(x + (size_t)(n0 + m) * 128 + c);
    float a = 0.f;
#pragma unroll
    for (int q = 0; q < 4; q++) { float4 v = xr[q]; a += v.x + v.y + v.z + v.w; }
#pragma unroll
    for (int o = 1; o < 8; o <<= 1) a += __shfl_xor(a, o, 64);
    if ((tid & 7) == 0) s_lds[m] = a;
  }
  __syncthreads();

  // cs0 -> split-bf16 LDS in A-frag layout (lane-linear b128 writes, conflict-free)
  {
    int m = lane, c = wv;  // row m, k-chunk [c*16, c*16+16)
    float s = s_lds[m];
    int kb = c * 16;
    int fb = ((m >> 5) * 8 + c) * FSTR + (m & 31) * 8;
#pragma unroll
    for (int u = 0; u < 2; u++) {
      unsigned uh[4], ul[4];
#pragma unroll
      for (int p = 0; p < 4; p++) {
        int k = kb + u * 8 + p * 2;
        unsigned short h0, l0, h1, l1;
        bsplit(eluf(fmaf(s, rwt0[k], tb0[k])), h0, l0);
        bsplit(eluf(fmaf(s, rwt0[k + 1], tb0[k + 1])), h1, l1);
        uh[p] = (unsigned)h0 | ((unsigned)h1 << 16);
        ul[p] = (unsigned)l0 | ((unsigned)l1 << 16);
      }
      *(uint4*)&csh[fb + u * 256] = make_uint4(uh[0], uh[1], uh[2], uh[3]);
      *(uint4*)&csl[fb + u * 256] = make_uint4(ul[0], ul[1], ul[2], ul[3]);
    }
  }
  __syncthreads();

  const int jc = cb * 32 + (lane & 31);
  // C-layout -> frag-layout store base (element crow goes to sbase + crow*8)
  const int sbase = (mg * 8 + cb * 2 + ((lane >> 4) & 1)) * FSTR +
                    ((lane >> 3) & 1) * 256 + (lane & 7);

  // ---- layer 0 GEMM: gi0 = cs0 @ wih0^T (3 independent acc chains) ----
  f32x16 g0[3] = {};
#pragma unroll
  for (int ks = 0; ks < 8; ks++) {
    bf16x8 ah = *(const bf16x8*)&csh[(mg * 8 + ks) * FSTR + lane * 8];
    bf16x8 al = *(const bf16x8*)&csl[(mg * 8 + ks) * FSTR + lane * 8];
#pragma unroll
    for (int g = 0; g < 3; g++) {
      int nt = g * 4 + cb;
      size_t base = (size_t)((nt * 8 + ks) * 64 + lane) * 8;
      bf16x8 bh = *(const bf16x8*)&w0ph[base];
      bf16x8 bl = *(const bf16x8*)&w0pl[base];
      MFMA3(g0[g], ah, al, bh, bl);
    }
  }

  // ---- GRU0 epilogue (h_s = s broadcast): h -> split-bf16 frags in LDS ----
  {
    float bir = bih0[jc], biz = bih0[jc + 128], bin_ = bih0[jc + 256];
    float bhr = bhh0[jc], bhz = bhh0[jc + 128], bhn = bhh0[jc + 256];
    float rwr = rwh0[jc], rwz = rwh0[jc + 128], rwn = rwh0[jc + 256];
#pragma unroll
    for (int reg = 0; reg < 16; reg++) {
      int crow = (reg & 3) + 8 * (reg >> 2) + 4 * (lane >> 5);
      int m = mg * 32 + crow;
      float s = s_lds[m];
      float dd = deg_lds[m];
      float r = sigm(g0[0][reg] + bir + fmaf(s, rwr, bhr));
      float z = sigm(g0[1][reg] + biz + fmaf(s, rwz, bhz));
      float nn2 = ftanh(fmaf(r, fmaf(s, rwn, bhn), g0[2][reg] + bin_));
      float v = dd * ((1.f - z) * nn2 + z * s);
      unsigned short vh, vl;
      bsplit(v, vh, vl);
      unsigned pv = (unsigned)vh | ((unsigned)vl << 16);
      unsigned pu = __shfl_xor(pv, 1, 64);
      if ((lane & 1) == 0) {
        int f = sbase + crow * 8;
        *(unsigned*)&hfh[f] = (pv & 0xFFFFu) | (pu << 16);
        *(unsigned*)&hfl[f] = (pv >> 16) | (pu & 0xFFFF0000u);
      }
    }
  }
  __syncthreads();  // h frags visible to all waves; all cs0 reads complete

  // ---- layer 1 phase A: t1 = h @ tw1^T AND gh = h @ whh1^T (4 indep chains) ----
  f32x16 a1 = {}, aR = {}, aZ = {}, aGHN = {};
#pragma unroll
  for (int ks = 0; ks < 8; ks++) {
    bf16x8 xh = *(const bf16x8*)&hfh[(mg * 8 + ks) * FSTR + lane * 8];
    bf16x8 xl = *(const bf16x8*)&hfl[(mg * 8 + ks) * FSTR + lane * 8];
    {
      size_t base = (size_t)((cb * 8 + ks) * 64 + lane) * 8;
      bf16x8 bh = *(const bf16x8*)&w1ph[base];
      bf16x8 bl = *(const bf16x8*)&w1pl[base];
      MFMA3(a1, xh, xl, bh, bl);
    }
#pragma unroll
    for (int g = 0; g < 3; g++) {
      size_t base = (size_t)(((12 + g * 4 + cb) * 8 + ks) * 64 + lane) * 8;
      bf16x8 bh = *(const bf16x8*)&w2ph[base];
      bf16x8 bl = *(const bf16x8*)&w2pl[base];
      if (g == 0) { MFMA3(aR, xh, xl, bh, bl); }
      else if (g == 1) { MFMA3(aZ, xh, xl, bh, bl); }
      else { MFMA3(aGHN, xh, xl, bh, bl); }
    }
  }

  // cs1 = elu(t1 + tb1) -> split-bf16 frags (reusing cs0 buffers)
  {
    float tbj = tb1[jc];
#pragma unroll
    for (int reg = 0; reg < 16; reg++) {
      int crow = (reg & 3) + 8 * (reg >> 2) + 4 * (lane >> 5);
      unsigned short vh, vl;
      bsplit(eluf(a1[reg] + tbj), vh, vl);
      unsigned pv = (unsigned)vh | ((unsigned)vl << 16);
      unsigned pu = __shfl_xor(pv, 1, 64);
      if ((lane & 1) == 0) {
        int f = sbase + crow * 8;
        *(unsigned*)&csh[f] = (pv & 0xFFFFu) | (pu << 16);
        *(unsigned*)&csl[f] = (pv >> 16) | (pu & 0xFFFF0000u);
      }
    }
  }
  __syncthreads();

  // ---- layer 1 phase B: gi = cs1 @ wih1^T (r,z merge into aR,aZ; n -> aGIN) ----
  f32x16 aGIN = {};
#pragma unroll
  for (int ks = 0; ks < 8; ks++) {
    bf16x8 ch = *(const bf16x8*)&csh[(mg * 8 + ks) * FSTR + lane * 8];
    bf16x8 cl = *(const bf16x8*)&csl[(mg * 8 + ks) * FSTR + lane * 8];
#pragma unroll
    for (int g = 0; g < 3; g++) {
      size_t base = (size_t)(((g * 4 + cb) * 8 + ks) * 64 + lane) * 8;
      bf16x8 bh = *(const bf16x8*)&w2ph[base];
      bf16x8 bl = *(const bf16x8*)&w2pl[base];
      if (g == 0) { MFMA3(aR, ch, cl, bh, bl); }
      else if (g == 1) { MFMA3(aZ, ch, cl, bh, bl); }
      else { MFMA3(aGIN, ch, cl, bh, bl); }
    }
  }

  // ---- GRU1 epilogue + deg scale ----
  {
    float bir = bih1[jc], biz = bih1[jc + 128], bin_ = bih1[jc + 256];
    float bhr = bhh1[jc], bhz = bhh1[jc + 128], bhn = bhh1[jc + 256];
#pragma unroll
    for (int reg = 0; reg < 16; reg++) {
      int crow = (reg & 3) + 8 * (reg >> 2) + 4 * (lane >> 5);
      int m = mg * 32 + crow;
      float dd = deg_lds[m];
      float r = sigm(aR[reg] + bir + bhr);
      float z = sigm(aZ[reg] + biz + bhz);
      float nn2 = ftanh(fmaf(r, aGHN[reg] + bhn, aGIN[reg] + bin_));
      int f = sbase + crow * 8;
      float hfull = (float)(*(const __bf16*)&hfh[f]) + (float)(*(const __bf16*)&hfl[f]);
      out[(size_t)(n0 + m) * 128 + jc] = dd * ((1.f - z) * nn2 + z * hfull);
    }
  }
}

extern "C" void kernel_launch(void* const* d_in, const int* in_sizes, int n_in,
                              void* d_out, int out_size, void* d_ws, size_t ws_size,
                              hipStream_t stream) {
  const float* x     = (const float*)d_in[0];
  const int*   edge  = (const int*)d_in[1];
  const float* attw0 = (const float*)d_in[4];
  const float* attb0 = (const float*)d_in[5];
  const float* wih0  = (const float*)d_in[6];
  const float* whh0  = (const float*)d_in[7];
  const float* bih0  = (const float*)d_in[8];
  const float* bhh0  = (const float*)d_in[9];
  const float* attw1 = (const float*)d_in[12];
  const float* attb1 = (const float*)d_in[13];
  const float* wih1  = (const float*)d_in[14];
  const float* whh1  = (const float*)d_in[15];
  const float* bih1  = (const float*)d_in[16];
  const float* bhh1  = (const float*)d_in[17];

  float* ws = (float*)d_ws;
  int*   deg  = (int*)(ws + 25600000);
  float* rwt0 = ws + 25800000;
  float* rwh0 = ws + 25800128;
  unsigned short* wp = (unsigned short*)(ws + 25800512);
  unsigned short* w0ph = wp;             // 49152 shorts
  unsigned short* w0pl = wp + 49152;
  unsigned short* w1ph = wp + 98304;     // 16384
  unsigned short* w1pl = wp + 114688;
  unsigned short* w2ph = wp + 131072;    // 98304
  unsigned short* w2pl = wp + 229376;    // end 327680 shorts

  const int* dst = edge + NE;  // edge_index[1]

  static bool attr_done = false;
  if (!attr_done) {
    hipFuncSetAttribute(reinterpret_cast<const void*>(fused_kernel),
                        hipFuncAttributeMaxDynamicSharedMemorySize, 66560);
    attr_done = true;
  }

  hipMemsetAsync(deg, 0, NN * sizeof(int), stream);
  prologue_kernel<<<2552, 256, 0, stream>>>(dst, deg, attw0, whh0, rwt0, rwh0,
                                            wih0, attw1, wih1, whh1,
                                            w0ph, w0pl, w1ph, w1pl, w2ph, w2pl);
  fused_kernel<<<NN / 64, 512, 66560, stream>>>(
      x, attb0, attb1, w0ph, w0pl, w1ph, w1pl, w2ph, w2pl,
      bih0, bhh0, rwt0, rwh0, bih1, bhh1, deg, (float*)d_out);
}